// Round 13
// baseline (76.647 us; speedup 1.0000x reference)
//
#include <hip/hip_runtime.h>
#include <math.h>

static constexpr int NPOS = 32 * 56 * 56;   // 100352 positions
static constexpr int CCH  = 256;
static constexpr int NBLK = 1792;           // NPOS / 56; 7 blocks/CU
static constexpr int PPB  = 56;             // positions per block (contiguous chunk)
static constexpr double EPSV = 1e-6;

typedef float f32x4 __attribute__((ext_vector_type(4)));

// ws layout (bytes):
//   S      [896] f64        @ 0       (7168 B)
//   partial[NBLK][896] f32  @ 12288   (1792*896*4 = 6422528 B)

__device__ __forceinline__ float eluf(float v) {
  return v > 0.f ? v : (__expf(v) - 1.f);
}

// ---------------------------------------------------------------------------
// Kernel 1: reduce, BLOCK-CHUNKED: block b reads positions [56b, 56b+56) —
// one sequential 57KB stream per block (DRAM row locality), 4 waves
// interleaved at 1KB granularity. Wave-private LDS transpose as before.
// stats: 0..3 sums(r,i,j,k); 4..13 rr,ri,rj,rk,ii,ij,ik,jj,jk,kk
// ---------------------------------------------------------------------------
__global__ __launch_bounds__(256) void hbn_reduce(const float* __restrict__ x,
                                                  float* __restrict__ partial) {
  const int tid  = threadIdx.x;
  const int lane = tid & 63;
  const int wib  = tid >> 6;
  const int dq   = lane & 15;
  const int base = blockIdx.x * PPB + wib;   // wave's first position

  __shared__ float stage[4][256];            // 1 KB per wave
  __shared__ float outs[4][896];
  float* st = &stage[wib][0];

  float acc[14][4];
#pragma unroll
  for (int s = 0; s < 14; ++s)
#pragma unroll
    for (int t = 0; t < 4; ++t) acc[s][t] = 0.f;

#pragma unroll 1
  for (int i = 0; i < PPB / 4; ++i) {        // 14 iterations, all in-bounds
    const int p = base + i * 4;
    const f32x4 v = *reinterpret_cast<const f32x4*>(x + (size_t)p * CCH + lane * 4);
    *reinterpret_cast<f32x4*>(st + lane * 4) = v;
    const f32x4 r4 = *reinterpret_cast<const f32x4*>(st + 0   + dq * 4);
    const f32x4 i4 = *reinterpret_cast<const f32x4*>(st + 64  + dq * 4);
    const f32x4 j4 = *reinterpret_cast<const f32x4*>(st + 128 + dq * 4);
    const f32x4 k4 = *reinterpret_cast<const f32x4*>(st + 192 + dq * 4);
#pragma unroll
    for (int t = 0; t < 4; ++t) {
      const float r = r4[t], i2 = i4[t], j = j4[t], k = k4[t];
      acc[0][t] += r;  acc[1][t] += i2;  acc[2][t] += j;  acc[3][t] += k;
      acc[4][t]  = fmaf(r,  r,  acc[4][t]);
      acc[5][t]  = fmaf(r,  i2, acc[5][t]);
      acc[6][t]  = fmaf(r,  j,  acc[6][t]);
      acc[7][t]  = fmaf(r,  k,  acc[7][t]);
      acc[8][t]  = fmaf(i2, i2, acc[8][t]);
      acc[9][t]  = fmaf(i2, j,  acc[9][t]);
      acc[10][t] = fmaf(i2, k,  acc[10][t]);
      acc[11][t] = fmaf(j,  j,  acc[11][t]);
      acc[12][t] = fmaf(j,  k,  acc[12][t]);
      acc[13][t] = fmaf(k,  k,  acc[13][t]);
    }
  }

  if (lane < 16) {
#pragma unroll
    for (int s = 0; s < 14; ++s)
#pragma unroll
      for (int t = 0; t < 4; ++t)
        outs[wib][s * 64 + dq * 4 + t] = acc[s][t];
  }
  __syncthreads();
  float* dst = partial + (size_t)blockIdx.x * 896;
  for (int idx = tid; idx < 896; idx += 256)
    dst[idx] = outs[0][idx] + outs[1][idx] + outs[2][idx] + outs[3][idx];
}

// ---------------------------------------------------------------------------
// Kernel 2: sum partials. Wave = one statistic; 28 loads/lane, f64 shfl.
// ---------------------------------------------------------------------------
__global__ __launch_bounds__(256) void hbn_sum(const float* __restrict__ partial,
                                               double* __restrict__ S) {
  const int lane = threadIdx.x & 63;
  const int s    = blockIdx.x * 4 + (threadIdx.x >> 6);
  if (s >= 896) return;
  double a = 0.0;
#pragma unroll
  for (int k = 0; k < NBLK / 64; ++k)        // 28
    a += (double)partial[(size_t)(k * 64 + lane) * 896 + s];
#pragma unroll
  for (int off = 32; off; off >>= 1) a += __shfl_down(a, off);
  if (lane == 0) S[s] = a;
}

// ---------------------------------------------------------------------------
// Solve one d: S sums -> cov -> f32 Jacobi -> M = G*V^{-1/2}, off = beta-M*mu
// ---------------------------------------------------------------------------
__device__ __forceinline__ void solve_one(const double* __restrict__ S,
                                          const float* __restrict__ beta,
                                          const float* __restrict__ grr, const float* __restrict__ gri,
                                          const float* __restrict__ grj, const float* __restrict__ grk,
                                          const float* __restrict__ gii, const float* __restrict__ gij,
                                          const float* __restrict__ gik, const float* __restrict__ gjj,
                                          const float* __restrict__ gjk, const float* __restrict__ gkk,
                                          int d, float* Mout /*16*/, float* offout /*4*/) {
  const double invM = 1.0 / (double)NPOS;
  double mu[4];
  mu[0] = S[0*64+d]*invM; mu[1] = S[1*64+d]*invM;
  mu[2] = S[2*64+d]*invM; mu[3] = S[3*64+d]*invM;

  float A[4][4];
  A[0][0] = (float)(S[4*64+d]*invM  - mu[0]*mu[0] + EPSV);
  A[0][1] = A[1][0] = (float)(S[5*64+d]*invM  - mu[0]*mu[1]);
  A[0][2] = A[2][0] = (float)(S[6*64+d]*invM  - mu[0]*mu[2]);
  A[0][3] = A[3][0] = (float)(S[7*64+d]*invM  - mu[0]*mu[3]);
  A[1][1] = (float)(S[8*64+d]*invM  - mu[1]*mu[1] + EPSV);
  A[1][2] = A[2][1] = (float)(S[9*64+d]*invM  - mu[1]*mu[2]);
  A[1][3] = A[3][1] = (float)(S[10*64+d]*invM - mu[1]*mu[3]);
  A[2][2] = (float)(S[11*64+d]*invM - mu[2]*mu[2] + EPSV);
  A[2][3] = A[3][2] = (float)(S[12*64+d]*invM - mu[2]*mu[3]);
  A[3][3] = (float)(S[13*64+d]*invM - mu[3]*mu[3] + EPSV);

  float U[4][4] = {{1,0,0,0},{0,1,0,0},{0,0,1,0},{0,0,0,1}};

#pragma unroll 1
  for (int sweep = 0; sweep < 6; ++sweep) {
#pragma unroll
    for (int p = 0; p < 3; ++p) {
#pragma unroll
      for (int q = p + 1; q < 4; ++q) {
        float apq = A[p][q];
        if (fabsf(apq) > 1e-30f) {
          float theta = (A[q][q] - A[p][p]) / (2.0f * apq);
          float t = 1.0f / (fabsf(theta) + sqrtf(fmaf(theta, theta, 1.0f)));
          if (theta < 0.0f) t = -t;
          float c = rsqrtf(fmaf(t, t, 1.0f));
          float s = t * c;
#pragma unroll
          for (int r = 0; r < 4; ++r) {
            float arp = A[r][p], arq = A[r][q];
            A[r][p] = c*arp - s*arq;  A[r][q] = s*arp + c*arq;
          }
#pragma unroll
          for (int r = 0; r < 4; ++r) {
            float apr = A[p][r], aqr = A[q][r];
            A[p][r] = c*apr - s*aqr;  A[q][r] = s*apr + c*aqr;
          }
#pragma unroll
          for (int r = 0; r < 4; ++r) {
            float urp = U[r][p], urq = U[r][q];
            U[r][p] = c*urp - s*urq;  U[r][q] = s*urp + c*urq;
          }
        }
      }
    }
  }

  float wis[4];
#pragma unroll
  for (int b = 0; b < 4; ++b) {
    float w = A[b][b];
    if (w < 1e-12f) w = 1e-12f;
    wis[b] = rsqrtf(w);
  }

  float Wm[4][4];
#pragma unroll
  for (int a = 0; a < 4; ++a)
#pragma unroll
    for (int cc = 0; cc < 4; ++cc) {
      float acc = 0.0f;
#pragma unroll
      for (int b = 0; b < 4; ++b) acc += U[a][b] * wis[b] * U[cc][b];
      Wm[a][cc] = acc;
    }

  float G[4][4];
  G[0][0] = grr[d]; G[0][1] = G[1][0] = gri[d];
  G[0][2] = G[2][0] = grj[d]; G[0][3] = G[3][0] = grk[d];
  G[1][1] = gii[d]; G[1][2] = G[2][1] = gij[d];
  G[1][3] = G[3][1] = gik[d];
  G[2][2] = gjj[d]; G[2][3] = G[3][2] = gjk[d];
  G[3][3] = gkk[d];

  float M[4][4];
#pragma unroll
  for (int e = 0; e < 4; ++e)
#pragma unroll
    for (int cc = 0; cc < 4; ++cc) {
      float acc = 0.0f;
#pragma unroll
      for (int b = 0; b < 4; ++b) acc += G[e][b] * Wm[b][cc];
      M[e][cc] = acc;
      Mout[e*4 + cc] = acc;
    }

#pragma unroll
  for (int e = 0; e < 4; ++e) {
    float acc = beta[e*64 + d];
#pragma unroll
    for (int cc = 0; cc < 4; ++cc) acc -= M[e][cc] * (float)mu[cc];
    offout[e] = acc;
  }
}

// ---------------------------------------------------------------------------
// Kernel 3: solve prologue + BLOCK-CHUNKED apply stream (same mapping as
// reduce: block b owns positions [56b, 56b+56), sequential read AND write).
// ---------------------------------------------------------------------------
__global__ __launch_bounds__(256) void hbn_apply(const float* __restrict__ x,
                                                 const double* __restrict__ S,
                                                 const float* __restrict__ beta,
                                                 const float* __restrict__ grr, const float* __restrict__ gri,
                                                 const float* __restrict__ grj, const float* __restrict__ grk,
                                                 const float* __restrict__ gii, const float* __restrict__ gij,
                                                 const float* __restrict__ gik, const float* __restrict__ gjj,
                                                 const float* __restrict__ gjk, const float* __restrict__ gkk,
                                                 float* __restrict__ out) {
  const int tid  = threadIdx.x;
  const int lane = tid & 63;
  const int wib  = tid >> 6;
  const int dq   = lane & 15;
  const int e    = lane >> 4;
  const int base = blockIdx.x * PPB + wib;

  __shared__ float stage[4][256];
  __shared__ float Ms[64 * 16];              // [(e*4+c)*64 + d]
  __shared__ float offs[256];                // [e*64 + d]
  float* st = &stage[wib][0];

  if (tid < 64) {
    float Mo[16], oo[4];
    solve_one(S, beta, grr, gri, grj, grk, gii, gij, gik, gjj, gjk, gkk,
              tid, Mo, oo);
#pragma unroll
    for (int ec = 0; ec < 16; ++ec) Ms[ec * 64 + tid] = Mo[ec];
#pragma unroll
    for (int q = 0; q < 4; ++q) offs[q * 64 + tid] = oo[q];
  }
  __syncthreads();

  f32x4 me[4];
#pragma unroll
  for (int c = 0; c < 4; ++c)
    me[c] = *reinterpret_cast<const f32x4*>(Ms + (e*4 + c)*64 + dq*4);
  const f32x4 ob = *reinterpret_cast<const f32x4*>(offs + e*64 + dq*4);

#pragma unroll 1
  for (int i = 0; i < PPB / 4; ++i) {        // 14 iterations
    const int p = base + i * 4;
    const f32x4 v = *reinterpret_cast<const f32x4*>(x + (size_t)p * CCH + lane * 4);
    *reinterpret_cast<f32x4*>(st + lane * 4) = v;
    const f32x4 r4 = *reinterpret_cast<const f32x4*>(st + 0   + dq * 4);
    const f32x4 i4 = *reinterpret_cast<const f32x4*>(st + 64  + dq * 4);
    const f32x4 j4 = *reinterpret_cast<const f32x4*>(st + 128 + dq * 4);
    const f32x4 k4 = *reinterpret_cast<const f32x4*>(st + 192 + dq * 4);

    f32x4 y;
#pragma unroll
    for (int t = 0; t < 4; ++t)
      y[t] = fmaf(me[0][t], r4[t],
             fmaf(me[1][t], i4[t],
             fmaf(me[2][t], j4[t],
             fmaf(me[3][t], k4[t], ob[t]))));
#pragma unroll
    for (int t = 0; t < 4; ++t) y[t] = eluf(y[t]);
    __builtin_nontemporal_store(y, reinterpret_cast<f32x4*>(out + (size_t)p * CCH + lane * 4));
  }
}

extern "C" void kernel_launch(void* const* d_in, const int* in_sizes, int n_in,
                              void* d_out, int out_size, void* d_ws, size_t ws_size,
                              hipStream_t stream) {
  (void)in_sizes; (void)n_in; (void)out_size; (void)ws_size;
  const float* x    = (const float*)d_in[0];
  const float* beta = (const float*)d_in[1];
  const float* grr  = (const float*)d_in[2];
  const float* gri  = (const float*)d_in[3];
  const float* grj  = (const float*)d_in[4];
  const float* grk  = (const float*)d_in[5];
  const float* gii  = (const float*)d_in[6];
  const float* gij  = (const float*)d_in[7];
  const float* gik  = (const float*)d_in[8];
  const float* gjj  = (const float*)d_in[9];
  const float* gjk  = (const float*)d_in[10];
  const float* gkk  = (const float*)d_in[11];
  float* out = (float*)d_out;

  double* S      = (double*)d_ws;                   // 896 f64
  float*  partial= (float*)((char*)d_ws + 12288);   // NBLK*896 f32

  hbn_reduce<<<NBLK, 256, 0, stream>>>(x, partial);
  hbn_sum<<<224, 256, 0, stream>>>(partial, S);
  hbn_apply<<<NBLK, 256, 0, stream>>>(x, S, beta, grr, gri, grj, grk,
                                      gii, gij, gik, gjj, gjk, gkk, out);
}

// Round 14
// 69.781 us; speedup vs baseline: 1.0984x; 1.0984x over previous
//
#include <hip/hip_runtime.h>
#include <math.h>

static constexpr int NPOS = 32 * 56 * 56;   // 100352 positions
static constexpr int HALF = NPOS / 2;       // 50176
static constexpr int CCH  = 256;
static constexpr int RB   = 1024;           // blocks for BOTH streaming kernels
static constexpr double EPSV = 1e-6;

typedef float f32x4 __attribute__((ext_vector_type(4)));

// ws layout (bytes):
//   S      [896] f64      @ 0       (7168 B)
//   partial[RB][896] f32  @ 12288   (3670016 B)

__device__ __forceinline__ float eluf(float v) {
  return v > 0.f ? v : (__expf(v) - 1.f);
}

// ---------------------------------------------------------------------------
// Kernel 1: reduce (R9/R11 proven structure, ~3 TB/s cold-read floor).
// Two independent 1KB streams per wave (low/high half) + wave-private LDS
// transpose. stats: 0..3 sums(r,i,j,k); 4..13 rr,ri,rj,rk,ii,ij,ik,jj,jk,kk
// ---------------------------------------------------------------------------
__global__ __launch_bounds__(256) void hbn_reduce(const float* __restrict__ x,
                                                  float* __restrict__ partial) {
  const int tid  = threadIdx.x;
  const int lane = tid & 63;
  const int wib  = tid >> 6;
  const int dq   = lane & 15;
  const int gw   = blockIdx.x * 4 + wib;
  const int nw   = RB * 4;                  // 4096 waves

  __shared__ float stage[4][512];           // 2 KB per wave
  __shared__ float outs[4][896];
  float* st = &stage[wib][0];

  float acc[14][4];
#pragma unroll
  for (int s = 0; s < 14; ++s)
#pragma unroll
    for (int t = 0; t < 4; ++t) acc[s][t] = 0.f;

  for (int p = gw; p < HALF; p += nw) {
    const f32x4 va = *reinterpret_cast<const f32x4*>(x + (size_t)p * CCH + lane * 4);
    const f32x4 vb = *reinterpret_cast<const f32x4*>(x + (size_t)(p + HALF) * CCH + lane * 4);
    *reinterpret_cast<f32x4*>(st + lane * 4)       = va;
    *reinterpret_cast<f32x4*>(st + 256 + lane * 4) = vb;
#pragma unroll
    for (int h = 0; h < 2; ++h) {
      const f32x4 r4 = *reinterpret_cast<const f32x4*>(st + h*256 + 0   + dq * 4);
      const f32x4 i4 = *reinterpret_cast<const f32x4*>(st + h*256 + 64  + dq * 4);
      const f32x4 j4 = *reinterpret_cast<const f32x4*>(st + h*256 + 128 + dq * 4);
      const f32x4 k4 = *reinterpret_cast<const f32x4*>(st + h*256 + 192 + dq * 4);
#pragma unroll
      for (int t = 0; t < 4; ++t) {
        const float r = r4[t], i = i4[t], j = j4[t], k = k4[t];
        acc[0][t] += r;  acc[1][t] += i;  acc[2][t] += j;  acc[3][t] += k;
        acc[4][t]  = fmaf(r, r, acc[4][t]);
        acc[5][t]  = fmaf(r, i, acc[5][t]);
        acc[6][t]  = fmaf(r, j, acc[6][t]);
        acc[7][t]  = fmaf(r, k, acc[7][t]);
        acc[8][t]  = fmaf(i, i, acc[8][t]);
        acc[9][t]  = fmaf(i, j, acc[9][t]);
        acc[10][t] = fmaf(i, k, acc[10][t]);
        acc[11][t] = fmaf(j, j, acc[11][t]);
        acc[12][t] = fmaf(j, k, acc[12][t]);
        acc[13][t] = fmaf(k, k, acc[13][t]);
      }
    }
  }

  if (lane < 16) {
#pragma unroll
    for (int s = 0; s < 14; ++s)
#pragma unroll
      for (int t = 0; t < 4; ++t)
        outs[wib][s * 64 + dq * 4 + t] = acc[s][t];
  }
  __syncthreads();
  float* dst = partial + (size_t)blockIdx.x * 896;
  for (int idx = tid; idx < 896; idx += 256)
    dst[idx] = outs[0][idx] + outs[1][idx] + outs[2][idx] + outs[3][idx];
}

// ---------------------------------------------------------------------------
// Kernel 2: sum partials. Wave = one statistic; 16 loads/lane, f64 shfl.
// ---------------------------------------------------------------------------
__global__ __launch_bounds__(256) void hbn_sum(const float* __restrict__ partial,
                                               double* __restrict__ S) {
  const int lane = threadIdx.x & 63;
  const int s    = blockIdx.x * 4 + (threadIdx.x >> 6);
  if (s >= 896) return;
  double a = 0.0;
#pragma unroll
  for (int k = 0; k < RB / 64; ++k)
    a += (double)partial[(size_t)(k * 64 + lane) * 896 + s];
#pragma unroll
  for (int off = 32; off; off >>= 1) a += __shfl_down(a, off);
  if (lane == 0) S[s] = a;
}

// ---------------------------------------------------------------------------
// Solve one d: S sums -> cov -> f32 Jacobi -> M = G*V^{-1/2}, off = beta-M*mu
// ---------------------------------------------------------------------------
__device__ __forceinline__ void solve_one(const double* __restrict__ S,
                                          const float* __restrict__ beta,
                                          const float* __restrict__ grr, const float* __restrict__ gri,
                                          const float* __restrict__ grj, const float* __restrict__ grk,
                                          const float* __restrict__ gii, const float* __restrict__ gij,
                                          const float* __restrict__ gik, const float* __restrict__ gjj,
                                          const float* __restrict__ gjk, const float* __restrict__ gkk,
                                          int d, float* Mout /*16*/, float* offout /*4*/) {
  const double invM = 1.0 / (double)NPOS;
  double mu[4];
  mu[0] = S[0*64+d]*invM; mu[1] = S[1*64+d]*invM;
  mu[2] = S[2*64+d]*invM; mu[3] = S[3*64+d]*invM;

  float A[4][4];
  A[0][0] = (float)(S[4*64+d]*invM  - mu[0]*mu[0] + EPSV);
  A[0][1] = A[1][0] = (float)(S[5*64+d]*invM  - mu[0]*mu[1]);
  A[0][2] = A[2][0] = (float)(S[6*64+d]*invM  - mu[0]*mu[2]);
  A[0][3] = A[3][0] = (float)(S[7*64+d]*invM  - mu[0]*mu[3]);
  A[1][1] = (float)(S[8*64+d]*invM  - mu[1]*mu[1] + EPSV);
  A[1][2] = A[2][1] = (float)(S[9*64+d]*invM  - mu[1]*mu[2]);
  A[1][3] = A[3][1] = (float)(S[10*64+d]*invM - mu[1]*mu[3]);
  A[2][2] = (float)(S[11*64+d]*invM - mu[2]*mu[2] + EPSV);
  A[2][3] = A[3][2] = (float)(S[12*64+d]*invM - mu[2]*mu[3]);
  A[3][3] = (float)(S[13*64+d]*invM - mu[3]*mu[3] + EPSV);

  float U[4][4] = {{1,0,0,0},{0,1,0,0},{0,0,1,0},{0,0,0,1}};

#pragma unroll 1
  for (int sweep = 0; sweep < 6; ++sweep) {
#pragma unroll
    for (int p = 0; p < 3; ++p) {
#pragma unroll
      for (int q = p + 1; q < 4; ++q) {
        float apq = A[p][q];
        if (fabsf(apq) > 1e-30f) {
          float theta = (A[q][q] - A[p][p]) / (2.0f * apq);
          float t = 1.0f / (fabsf(theta) + sqrtf(fmaf(theta, theta, 1.0f)));
          if (theta < 0.0f) t = -t;
          float c = rsqrtf(fmaf(t, t, 1.0f));
          float s = t * c;
#pragma unroll
          for (int r = 0; r < 4; ++r) {
            float arp = A[r][p], arq = A[r][q];
            A[r][p] = c*arp - s*arq;  A[r][q] = s*arp + c*arq;
          }
#pragma unroll
          for (int r = 0; r < 4; ++r) {
            float apr = A[p][r], aqr = A[q][r];
            A[p][r] = c*apr - s*aqr;  A[q][r] = s*apr + c*aqr;
          }
#pragma unroll
          for (int r = 0; r < 4; ++r) {
            float urp = U[r][p], urq = U[r][q];
            U[r][p] = c*urp - s*urq;  U[r][q] = s*urp + c*urq;
          }
        }
      }
    }
  }

  float wis[4];
#pragma unroll
  for (int b = 0; b < 4; ++b) {
    float w = A[b][b];
    if (w < 1e-12f) w = 1e-12f;
    wis[b] = rsqrtf(w);
  }

  float Wm[4][4];
#pragma unroll
  for (int a = 0; a < 4; ++a)
#pragma unroll
    for (int cc = 0; cc < 4; ++cc) {
      float acc = 0.0f;
#pragma unroll
      for (int b = 0; b < 4; ++b) acc += U[a][b] * wis[b] * U[cc][b];
      Wm[a][cc] = acc;
    }

  float G[4][4];
  G[0][0] = grr[d]; G[0][1] = G[1][0] = gri[d];
  G[0][2] = G[2][0] = grj[d]; G[0][3] = G[3][0] = grk[d];
  G[1][1] = gii[d]; G[1][2] = G[2][1] = gij[d];
  G[1][3] = G[3][1] = gik[d];
  G[2][2] = gjj[d]; G[2][3] = G[3][2] = gjk[d];
  G[3][3] = gkk[d];

  float M[4][4];
#pragma unroll
  for (int e = 0; e < 4; ++e)
#pragma unroll
    for (int cc = 0; cc < 4; ++cc) {
      float acc = 0.0f;
#pragma unroll
      for (int b = 0; b < 4; ++b) acc += G[e][b] * Wm[b][cc];
      M[e][cc] = acc;
      Mout[e*4 + cc] = acc;
    }

#pragma unroll
  for (int e = 0; e < 4; ++e) {
    float acc = beta[e*64 + d];
#pragma unroll
    for (int cc = 0; cc < 4; ++cc) acc -= M[e][cc] * (float)mu[cc];
    offout[e] = acc;
  }
}

// ---------------------------------------------------------------------------
// Kernel 3: solve prologue + apply. IDENTICAL grid & position mapping as
// hbn_reduce (block b covers the same positions in the same order) so that,
// with round-robin block->XCD placement, apply block b reuses the L2 lines
// reduce block b just fetched. NT stores.
// ---------------------------------------------------------------------------
__global__ __launch_bounds__(256) void hbn_apply(const float* __restrict__ x,
                                                 const double* __restrict__ S,
                                                 const float* __restrict__ beta,
                                                 const float* __restrict__ grr, const float* __restrict__ gri,
                                                 const float* __restrict__ grj, const float* __restrict__ grk,
                                                 const float* __restrict__ gii, const float* __restrict__ gij,
                                                 const float* __restrict__ gik, const float* __restrict__ gjj,
                                                 const float* __restrict__ gjk, const float* __restrict__ gkk,
                                                 float* __restrict__ out) {
  const int tid  = threadIdx.x;
  const int lane = tid & 63;
  const int wib  = tid >> 6;
  const int dq   = lane & 15;
  const int e    = lane >> 4;
  const int gw   = blockIdx.x * 4 + wib;
  const int nw   = RB * 4;                   // same 4096-wave mapping as reduce

  __shared__ float stage[4][512];
  __shared__ float Ms[64 * 16];              // [(e*4+c)*64 + d]
  __shared__ float offs[256];                // [e*64 + d]
  float* st = &stage[wib][0];

  if (tid < 64) {
    float Mo[16], oo[4];
    solve_one(S, beta, grr, gri, grj, grk, gii, gij, gik, gjj, gjk, gkk,
              tid, Mo, oo);
#pragma unroll
    for (int ec = 0; ec < 16; ++ec) Ms[ec * 64 + tid] = Mo[ec];
#pragma unroll
    for (int q = 0; q < 4; ++q) offs[q * 64 + tid] = oo[q];
  }
  __syncthreads();

  f32x4 me[4];
#pragma unroll
  for (int c = 0; c < 4; ++c)
    me[c] = *reinterpret_cast<const f32x4*>(Ms + (e*4 + c)*64 + dq*4);
  const f32x4 ob = *reinterpret_cast<const f32x4*>(offs + e*64 + dq*4);

  for (int p = gw; p < HALF; p += nw) {
    const f32x4 va = *reinterpret_cast<const f32x4*>(x + (size_t)p * CCH + lane * 4);
    const f32x4 vb = *reinterpret_cast<const f32x4*>(x + (size_t)(p + HALF) * CCH + lane * 4);
    *reinterpret_cast<f32x4*>(st + lane * 4)       = va;
    *reinterpret_cast<f32x4*>(st + 256 + lane * 4) = vb;
#pragma unroll
    for (int h = 0; h < 2; ++h) {
      const f32x4 r4 = *reinterpret_cast<const f32x4*>(st + h*256 + 0   + dq * 4);
      const f32x4 i4 = *reinterpret_cast<const f32x4*>(st + h*256 + 64  + dq * 4);
      const f32x4 j4 = *reinterpret_cast<const f32x4*>(st + h*256 + 128 + dq * 4);
      const f32x4 k4 = *reinterpret_cast<const f32x4*>(st + h*256 + 192 + dq * 4);

      f32x4 y;
#pragma unroll
      for (int t = 0; t < 4; ++t)
        y[t] = fmaf(me[0][t], r4[t],
               fmaf(me[1][t], i4[t],
               fmaf(me[2][t], j4[t],
               fmaf(me[3][t], k4[t], ob[t]))));
#pragma unroll
      for (int t = 0; t < 4; ++t) y[t] = eluf(y[t]);
      const size_t po = (size_t)(h == 0 ? p : p + HALF) * CCH + lane * 4;
      __builtin_nontemporal_store(y, reinterpret_cast<f32x4*>(out + po));
    }
  }
}

extern "C" void kernel_launch(void* const* d_in, const int* in_sizes, int n_in,
                              void* d_out, int out_size, void* d_ws, size_t ws_size,
                              hipStream_t stream) {
  (void)in_sizes; (void)n_in; (void)out_size; (void)ws_size;
  const float* x    = (const float*)d_in[0];
  const float* beta = (const float*)d_in[1];
  const float* grr  = (const float*)d_in[2];
  const float* gri  = (const float*)d_in[3];
  const float* grj  = (const float*)d_in[4];
  const float* grk  = (const float*)d_in[5];
  const float* gii  = (const float*)d_in[6];
  const float* gij  = (const float*)d_in[7];
  const float* gik  = (const float*)d_in[8];
  const float* gjj  = (const float*)d_in[9];
  const float* gjk  = (const float*)d_in[10];
  const float* gkk  = (const float*)d_in[11];
  float* out = (float*)d_out;

  double* S      = (double*)d_ws;                   // 896 f64
  float*  partial= (float*)((char*)d_ws + 12288);   // RB*896 f32

  hbn_reduce<<<RB, 256, 0, stream>>>(x, partial);
  hbn_sum<<<224, 256, 0, stream>>>(partial, S);
  hbn_apply<<<RB, 256, 0, stream>>>(x, S, beta, grr, gri, grj, grk,
                                    gii, gij, gik, gjj, gjk, gkk, out);
}